// Round 12
// baseline (578.335 us; speedup 1.0000x reference)
//
#include <hip/hip_runtime.h>
#include <math.h>

#define BB 4
#define HH 4
#define NN 2048
#define DD 256
#define HDIM 64
#define NTOK 8192
#define NTOK2 16384

typedef __attribute__((ext_vector_type(8))) __bf16 bf16x8;
typedef __attribute__((ext_vector_type(8))) unsigned short ushort8;
typedef __attribute__((ext_vector_type(4))) float floatx4;
typedef __attribute__((ext_vector_type(4))) short short4v;

union U8 { ushort8 u; bf16x8 b; };
union U4 { unsigned int u[2]; unsigned long long l; short4v s; };

// v_mfma_f32_16x16x16_bf16 (K=16): A/B = 4 bf16 (short4), C/D = 4 f32.
#define MFMA16(a, b, c) __builtin_amdgcn_mfma_f32_16x16x16bf16_1k(a, b, c, 0, 0, 0)

__device__ __forceinline__ unsigned short f2bf(float x) {
    unsigned int u = __float_as_uint(x);
    u += 0x7FFF + ((u >> 16) & 1);
    return (unsigned short)(u >> 16);
}
__device__ __forceinline__ float bf2f(unsigned short u) {
    return __uint_as_float(((unsigned int)u) << 16);
}
// hardware packed f32->bf16 convert (RNE): lo16 = a, hi16 = b, one VALU op
__device__ __forceinline__ unsigned int cvtpk(float a, float b) {
    unsigned int r;
    asm("v_cvt_pk_bf16_f32 %0, %1, %2" : "=v"(r) : "v"(a), "v"(b));
    return r;
}
__device__ __forceinline__ floatx4 fmax4(floatx4 a, floatx4 b) {
    floatx4 r;
    r[0] = fmaxf(a[0], b[0]); r[1] = fmaxf(a[1], b[1]);
    r[2] = fmaxf(a[2], b[2]); r[3] = fmaxf(a[3], b[3]);
    return r;
}

// ---------------------------------------------------------------------------
// Weight transpose+convert: W[K][N] f32 -> Wt[N][st] bf16 (st = output row
// stride in k; lets W1 top-halves land in 512-stride composite buffers).
// ---------------------------------------------------------------------------
struct WTab {
    const float* w[7];
    unsigned short* o[7];
    int K[7];
    int N[7];
    int st[7];
    int t0[8];
};

__global__ __launch_bounds__(256) void wtrans(WTab tab)
{
    __shared__ float lds[32][33];
    const int t = threadIdx.x;
    int bid = blockIdx.x;
    int s = 0;
    while (bid >= tab.t0[s + 1]) s++;
    const int ti = bid - tab.t0[s];
    const int K = tab.K[s], N = tab.N[s], st = tab.st[s];
    const int tx = ti % (N / 32), ty = ti / (N / 32);
    const int k0 = ty * 32, n0 = tx * 32;
    const float* W = tab.w[s];
    unsigned short* Wt = tab.o[s];

    {
        int r = t >> 3, c = (t & 7) * 4;
        float4 a = *(const float4*)&W[(size_t)(k0 + r) * N + n0 + c];
        lds[r][c] = a.x; lds[r][c+1] = a.y; lds[r][c+2] = a.z; lds[r][c+3] = a.w;
    }
    __syncthreads();
    {
        int n = t >> 3, kq = (t & 7) * 4;
        ushort4 p;
        p.x = f2bf(lds[kq+0][n]); p.y = f2bf(lds[kq+1][n]);
        p.z = f2bf(lds[kq+2][n]); p.w = f2bf(lds[kq+3][n]);
        *(ushort4*)&Wt[(size_t)(n0 + n) * st + k0 + kq] = p;
    }
}

// ---------------------------------------------------------------------------
// Weight fusion: Weff_bot[i][n] = sum_j Wo[i][j] * W1[256+j][n], written
// transposed-bf16 into out[n][256+i] (512-stride).  grid 128: seg = bid>>6.
// ---------------------------------------------------------------------------
__global__ __launch_bounds__(256) void wfuse(
    const float* __restrict__ Wo_s, const float* __restrict__ W1_s,
    unsigned short* __restrict__ o_s,
    const float* __restrict__ Wo_c, const float* __restrict__ W1_c,
    unsigned short* __restrict__ o_c)
{
    __shared__ float wo[32][33];
    __shared__ float w1[32][68];
    const int t = threadIdx.x;
    const int bid = blockIdx.x;
    const int seg = bid >> 6, ti_ = bid & 63;
    const int i0 = (ti_ >> 3) * 32, n0 = (ti_ & 7) * 64;
    const float* Wo  = seg ? Wo_c : Wo_s;
    const float* W1b = (seg ? W1_c : W1_s) + 256 * 512;
    unsigned short* out = seg ? o_c : o_s;
    const int ti = t >> 3, tn = t & 7;

    float acc[8] = {};
    for (int jc = 0; jc < 256; jc += 32) {
        {
            int r = t >> 3, c = (t & 7) * 4;
            *(float4*)&wo[r][c] = *(const float4*)&Wo[(size_t)(i0 + r) * 256 + jc + c];
            int c8 = (t & 7) * 8;
            *(float4*)&w1[r][c8]     = *(const float4*)&W1b[(size_t)(jc + r) * 512 + n0 + c8];
            *(float4*)&w1[r][c8 + 4] = *(const float4*)&W1b[(size_t)(jc + r) * 512 + n0 + c8 + 4];
        }
        __syncthreads();
        #pragma unroll
        for (int j = 0; j < 32; j++) {
            float a = wo[ti][j];
            #pragma unroll
            for (int e = 0; e < 8; e++) acc[e] += a * w1[j][tn * 8 + e];
        }
        __syncthreads();
    }
    #pragma unroll
    for (int e = 0; e < 8; e++)
        out[(size_t)(n0 + tn * 8 + e) * 512 + 256 + i0 + ti] = f2bf(acc[e]);
}

// ---------------------------------------------------------------------------
// Bias fusion: beff[n] = b1[n] + sum_j bo[j] * W1[256+j][n].
// grid 1024 (seg*512 + n); block reduces the 256-term dot product.
// ---------------------------------------------------------------------------
__global__ __launch_bounds__(256) void bfuse(
    const float* bo_s, const float* W1_s, const float* b1_s, float* bs,
    const float* bo_c, const float* W1_c, const float* b1_c, float* bc)
{
    __shared__ float r[4];
    const int bid = blockIdx.x;
    const int seg = bid >> 9, n = bid & 511;
    const float* bo  = seg ? bo_c : bo_s;
    const float* W1b = (seg ? W1_c : W1_s) + 256 * 512;
    const float* b1  = seg ? b1_c : b1_s;
    float* out       = seg ? bc : bs;
    const int j = threadIdx.x;
    float a = bo[j] * W1b[(size_t)j * 512 + n];
    #pragma unroll
    for (int o = 32; o > 0; o >>= 1) a += __shfl_xor(a, o, 64);
    if ((j & 63) == 0) r[j >> 6] = a;
    __syncthreads();
    if (j == 0) out[n] = b1[n] + r[0] + r[1] + r[2] + r[3];
}

// ---------------------------------------------------------------------------
// bf16 MFMA GEMM, 64x128 tile, ZERO-LDS / ZERO-BARRIER: A and B fragments
// are read DIRECTLY from global (L2-resident operands -- B <= 512KB weights,
// A panel hot).  Per fragment read, lanes (l15,quad) cover 16 rows x 4
// consecutive 16B chunks = 16 fully-utilized 64B lines.  Per K-step a wave
// issues 12 independent loads then 16 MFMAs with no synchronization of any
// kind; multi-wave TLP hides the ~200cy L2 latency.  This attacks the
// measured failure mode of all staged variants (R4: every pipe <8% busy --
// barrier-serialized stage->consume at short K).
// (Falsified alternatives: global_load_lds R2/R4; BM=128 R6; dbuf 1-barrier
// R7; RoPE-fused epilogue R9.)
// modes: 1 bf16 row-major | 2 bf16 dual scatter (col<256 -> rows [bh][n][d],
//        col>=256 -> V^T [bh][d][n]) | 3 qkv scatter (V transposed) |
//        4 f32 = acc+bias+R (+ bf16 copies to outH0 [.,256] / outH1 [.,512])
// ---------------------------------------------------------------------------
__global__ __launch_bounds__(256) void gemm_mfma(
    const unsigned short* __restrict__ A, int lda,
    const unsigned short* __restrict__ Wt, int K,
    const float* __restrict__ bias, const float* __restrict__ bias2, int mode,
    float* outF, unsigned short* outH0, unsigned short* outH1,
    unsigned short* outH2,
    int ldc, const float* R0, const float* R1)
{
    const int t = threadIdx.x;
    const int w = t >> 6, lane = t & 63, quad = lane >> 4, l15 = lane & 15;
    const int m0 = blockIdx.y * 64, n0 = blockIdx.x * 128;
    const int wn = w * 32;

    // per-lane fragment base pointers (k advances along the row)
    const unsigned short* Ar = A  + (size_t)(m0 + l15) * lda      + quad * 8;
    const unsigned short* Br = Wt + (size_t)(n0 + wn + l15) * K   + quad * 8;
    const size_t a16 = (size_t)16 * lda;    // 16-row stride in A
    const size_t b16 = (size_t)16 * K;      // 16-row stride in B

    floatx4 acc[4][2];
    #pragma unroll
    for (int i = 0; i < 4; i++)
        #pragma unroll
        for (int j = 0; j < 2; j++) acc[i][j] = (floatx4){0.f, 0.f, 0.f, 0.f};

    const int nk = K >> 5;   // 32-wide K sub-steps
    for (int kk = 0; kk < nk; kk++) {
        const int ko = kk * 32;
        U8 af[4], bf[2];
        #pragma unroll
        for (int i = 0; i < 4; i++)
            af[i].u = *(const ushort8*)(Ar + (size_t)i * a16 + ko);
        #pragma unroll
        for (int j = 0; j < 2; j++)
            bf[j].u = *(const ushort8*)(Br + (size_t)j * b16 + ko);
        #pragma unroll
        for (int i = 0; i < 4; i++)
            #pragma unroll
            for (int j = 0; j < 2; j++)
                acc[i][j] = __builtin_amdgcn_mfma_f32_16x16x32_bf16(af[i].b, bf[j].b, acc[i][j], 0, 0, 0);
    }

    #pragma unroll
    for (int i = 0; i < 4; i++) {
        #pragma unroll
        for (int j = 0; j < 2; j++) {
            int col = n0 + wn + j * 16 + l15;
            float bv = (mode == 2 && col >= 256) ? bias2[col & 255] : bias[col];
            #pragma unroll
            for (int r = 0; r < 4; r++) {
                int grow = m0 + i * 16 + quad * 4 + r;
                float v = acc[i][j][r] + bv;
                if (mode == 1) {
                    outH0[(size_t)grow * ldc + col] = f2bf(v);
                } else if (mode == 2) {
                    int cc = col & 255;
                    int h = cc >> 6, d = cc & 63;
                    int ds = grow >> 13, b = (grow >> 11) & 3, n = grow & 2047;
                    int bh = ds * 16 + b * 4 + h;
                    if (col < 256)
                        outH0[((size_t)bh * NN + n) * HDIM + d] = f2bf(v);
                    else  // V^T layout [bh][hd][n]
                        outH1[((size_t)bh * HDIM + d) * NN + n] = f2bf(v);
                } else if (mode == 3) {
                    int sel = col % 3, cc = col / 3;
                    int h = cc >> 6, d = cc & 63;
                    int ds = grow >> 13, b = (grow >> 11) & 3, n = grow & 2047;
                    int bh = ds * 16 + b * 4 + h;
                    if (sel == 0)
                        outH0[((size_t)bh * NN + n) * HDIM + d] = f2bf(v);
                    else if (sel == 1)
                        outH1[((size_t)bh * NN + n) * HDIM + d] = f2bf(v);
                    else  // V^T layout [bh][hd][n]
                        outH2[((size_t)bh * HDIM + d) * NN + n] = f2bf(v);
                } else {
                    const float* R = (grow < NTOK) ? R0 : R1;
                    float vv = v + R[(size_t)(grow & 8191) * 256 + col];
                    outF[(size_t)grow * 256 + col] = vv;
                    if (outH0) outH0[(size_t)grow * 256 + col] = f2bf(vv);
                    if (outH1) outH1[(size_t)grow * 512 + col] = f2bf(vv);
                }
            }
        }
    }
}

// ---------------------------------------------------------------------------
// RoPE in place on qb and kb (bf16 [32][2048][64]); enc0/enc1 f32 [2,B,1,N,HD].
// ---------------------------------------------------------------------------
__global__ __launch_bounds__(256) void rope_k(unsigned short* __restrict__ qb,
                                              unsigned short* __restrict__ kb,
                                              const float* __restrict__ enc0,
                                              const float* __restrict__ enc1)
{
    int i = blockIdx.x * 256 + threadIdx.x;     // 2^22 pair slots
    int dp = (i & 31) * 2;
    int n  = (i >> 5) & (NN - 1);
    int h  = (i >> 16) & 3;
    int b  = (i >> 18) & 3;
    int ds = (i >> 20) & 1;
    int bf = (i >> 21) & 1;
    unsigned short* tq = (bf ? kb : qb) +
        (((size_t)(ds * 16 + b * 4 + h)) * NN + n) * HDIM + dp;
    const float* e0 = (ds ? enc1 : enc0) + ((size_t)b * NN + n) * HDIM + dp;
    const float* e1 = e0 + (size_t)BB * NN * HDIM;
    float x0 = bf2f(tq[0]), x1 = bf2f(tq[1]);
    float y0 = x0 * e0[0] - x1 * e1[0];
    float y1 = x1 * e0[1] + x0 * e1[1];
    tq[0] = f2bf(y0); tq[1] = f2bf(y1);
}

// ---------------------------------------------------------------------------
// MFMA bf16 flash attention, S^T formulation.  Q,K row-major [32][2048][64];
// V PRE-TRANSPOSED [32][64][2048].  QBLK=64: each of 4 waves owns 16 q-rows
// (single MFMA group) -> grid 1024 blocks = 4 blocks/CU.  KVBLK=64 double-
// buffered LDS, single __syncthreads per step.  Per-lane online softmax with
// defer-max rescale skip (THR=8, exp2 domain), v_cvt_pk_bf16_f32 packing,
// cross-quad l-reduction deferred to the epilogue.  ISSUE-SATURATED at this
// point (VALU 70% + MFMA 24%): flash's floor for this algorithm.
// KV head = bh ^ kvx.  qscale incl log2e.
// ---------------------------------------------------------------------------
__global__ __launch_bounds__(256) void flash_attn(
    const unsigned short* __restrict__ Q, const unsigned short* __restrict__ K,
    const unsigned short* __restrict__ V, unsigned short* __restrict__ O,
    int ldo, int kvx, float qscale)
{
    __shared__ __align__(16) unsigned short Ks[2][64 * 72];    // [key][hd]
    __shared__ __align__(16) unsigned short Vt[2][64 * 72];    // [hd][key]

    const int t    = threadIdx.x;
    const int w    = t >> 6;
    const int lane = t & 63;
    const int quad = lane >> 4;
    const int l15  = lane & 15;
    const int bh   = blockIdx.y;
    const int kbh  = bh ^ kvx;
    const int q0   = blockIdx.x * 64;

    const unsigned short* Qb  = Q + (size_t)bh  * NN * HDIM;
    const unsigned short* Kb  = K + (size_t)kbh * NN * HDIM;
    const unsigned short* VTb = V + (size_t)kbh * NN * HDIM;   // [hd][n]

    const int srf = t >> 3, scf = (t & 7) * 8;

    // Q fragments: lane l15 = q-row, k(hd) = quad*8+j  (B-operand of K·Q^T)
    bf16x8 qf0, qf1;
    {
        const int qrow = q0 + w * 16 + l15;
        U8 r0, r1, x0, x1;
        r0.u = *(const ushort8*)&Qb[(size_t)qrow * HDIM + quad * 8];
        r1.u = *(const ushort8*)&Qb[(size_t)qrow * HDIM + 32 + quad * 8];
        #pragma unroll
        for (int j = 0; j < 8; j++) {
            x0.u[j] = f2bf(bf2f(r0.u[j]) * qscale);
            x1.u[j] = f2bf(bf2f(r1.u[j]) * qscale);
        }
        qf0 = x0.b; qf1 = x1.b;
    }

    floatx4 o[4];   // O^T accumulator: col = q = l15, row(hd) = c*16+quad*4+r
    #pragma unroll
    for (int c = 0; c < 4; c++) o[c] = (floatx4){0.f, 0.f, 0.f, 0.f};
    float m = -1e30f, l = 0.f;   // l is a per-lane PARTIAL (this quad's keys)

    // tile 0: load + stage into buffer 0
    ushort8 ka0 = *(const ushort8*)&Kb[(size_t)srf * HDIM + scf];
    ushort8 ka1 = *(const ushort8*)&Kb[(size_t)(srf + 32) * HDIM + scf];
    ushort8 va0 = *(const ushort8*)&VTb[(size_t)srf * NN + scf];
    ushort8 va1 = *(const ushort8*)&VTb[(size_t)(srf + 32) * NN + scf];
    *(ushort8*)&Ks[0][srf * 72 + scf]        = ka0;
    *(ushort8*)&Ks[0][(srf + 32) * 72 + scf] = ka1;
    *(ushort8*)&Vt[0][srf * 72 + scf]        = va0;
    *(ushort8*)&Vt[0][(srf + 32) * 72 + scf] = va1;
    __syncthreads();

    int cur = 0;
    for (int j0 = 0; j0 < NN; j0 += 64, cur ^= 1) {
        const int more = (j0 + 64 < NN);
        if (more) {
            const int jn = j0 + 64;
            ka0 = *(const ushort8*)&Kb[(size_t)(jn + srf) * HDIM + scf];
            ka1 = *(const ushort8*)&Kb[(size_t)(jn + srf + 32) * HDIM + scf];
            va0 = *(const ushort8*)&VTb[(size_t)srf * NN + jn + scf];
            va1 = *(const ushort8*)&VTb[(size_t)(srf + 32) * NN + jn + scf];
        }

        // S^T = K (qscale*Q)^T : s[t4]: col = q = l15, row(key) = quad*4 + r
        floatx4 s[4];
        __builtin_amdgcn_s_setprio(1);
        #pragma unroll
        for (int t4 = 0; t4 < 4; t4++) {
            U8 k0, k1;
            k0.u = *(const ushort8*)&Ks[cur][(t4 * 16 + l15) * 72 + quad * 8];
            k1.u = *(const ushort8*)&Ks[cur][(t4 * 16 + l15) * 72 + 32 + quad * 8];
            floatx4 z = (floatx4){0.f, 0.f, 0.f, 0.f};
            z = __builtin_amdgcn_mfma_f32_16x16x32_bf16(k0.b, qf0, z, 0, 0, 0);
            z = __builtin_amdgcn_mfma_f32_16x16x32_bf16(k1.b, qf1, z, 0, 0, 0);
            s[t4] = z;
        }
        __builtin_amdgcn_s_setprio(0);

        // per-lane online softmax (one q-row per lane; keys split across quads)
        floatx4 a = fmax4(fmax4(s[0], s[1]), fmax4(s[2], s[3]));
        float mx = fmaxf(fmaxf(a[0], a[1]), fmaxf(a[2], a[3]));
        mx = fmaxf(mx, __shfl_xor(mx, 16, 64));
        mx = fmaxf(mx, __shfl_xor(mx, 32, 64));
        // defer-max: skip the O/l rescale while max growth stays < 8
        // (exp2 domain -> P bounded by 256; harmless in f32 accum)
        if (!__all(mx <= m + 8.f)) {
            float mn = fmaxf(m, mx);
            float al = exp2f(m - mn);
            m = mn;
            l *= al;
            #pragma unroll
            for (int c = 0; c < 4; c++)
                #pragma unroll
                for (int r = 0; r < 4; r++) o[c][r] *= al;
        }
        float rs = 0.f;
        #pragma unroll
        for (int t4 = 0; t4 < 4; t4++)
            #pragma unroll
            for (int r = 0; r < 4; r++) {
                float p = exp2f(s[t4][r] - m);
                s[t4][r] = p;
                rs += p;
            }
        l += rs;   // per-lane partial; cross-quad reduce deferred to epilogue

        // pack P^T fragments: C/D layout of S^T == B-operand of 16x16x16
        short4v pf[4];
        #pragma unroll
        for (int t4 = 0; t4 < 4; t4++) {
            U4 pk;
            pk.u[0] = cvtpk(s[t4][0], s[t4][1]);
            pk.u[1] = cvtpk(s[t4][2], s[t4][3]);
            pf[t4] = pk.s;
        }

        // O^T += V^T P^T : A = V^T chunk [hd=c*16+l15][key=t4*16+quad*4+j]
        __builtin_amdgcn_s_setprio(1);
        #pragma unroll
        for (int c = 0; c < 4; c++) {
            U4 vf[4];
            #pragma unroll
            for (int t4 = 0; t4 < 4; t4++)
                vf[t4].l = *(const unsigned long long*)
                    &Vt[cur][(c * 16 + l15) * 72 + t4 * 16 + quad * 4];
            #pragma unroll
            for (int t4 = 0; t4 < 4; t4++)
                o[c] = MFMA16(vf[t4].s, pf[t4], o[c]);
        }
        __builtin_amdgcn_s_setprio(0);

        // stage next tile into the other buffer; single barrier per step
        // (safe: buf cur^1 was last read before the PREVIOUS barrier)
        if (more) {
            *(ushort8*)&Ks[cur ^ 1][srf * 72 + scf]        = ka0;
            *(ushort8*)&Ks[cur ^ 1][(srf + 32) * 72 + scf] = ka1;
            *(ushort8*)&Vt[cur ^ 1][srf * 72 + scf]        = va0;
            *(ushort8*)&Vt[cur ^ 1][(srf + 32) * 72 + scf] = va1;
            __syncthreads();
        }
    }

    // epilogue: cross-quad l reduce, normalize, write bf16 at stride ldo
    l += __shfl_xor(l, 16, 64);
    l += __shfl_xor(l, 32, 64);
    const int ds = bh >> 4, b = (bh >> 2) & 3, h = bh & 3;
    const int q = q0 + w * 16 + l15;
    const size_t row = (size_t)ds * NTOK + b * NN + q;
    float inv = 1.f / l;
    #pragma unroll
    for (int c = 0; c < 4; c++) {
        U4 pk;
        pk.u[0] = cvtpk(o[c][0] * inv, o[c][1] * inv);
        pk.u[1] = cvtpk(o[c][2] * inv, o[c][3] * inv);
        *(unsigned long long*)&O[row * ldo + h * HDIM + c * 16 + quad * 4] = pk.l;
    }
}

// ---------------------------------------------------------------------------
// LayerNorm + exact GELU, bf16 in-place, row width 512.
// One WAVE per row (64 lanes x 8 elems, ushort8 vector loads), pure-shuffle
// reduction, no LDS, no barrier.  Block = 4 waves = 4 rows.
// ---------------------------------------------------------------------------
__global__ __launch_bounds__(256) void ln_gelu(
    unsigned short* __restrict__ hb, const float* __restrict__ g,
    const float* __restrict__ be)
{
    const int lane = threadIdx.x & 63;
    const int wv   = threadIdx.x >> 6;
    const size_t row = (size_t)blockIdx.x * 4 + wv;
    unsigned short* ip = hb + row * 512 + lane * 8;
    U8 v; v.u = *(const ushort8*)ip;
    float x[8];
    float s = 0.f, ss = 0.f;
    #pragma unroll
    for (int j = 0; j < 8; j++) {
        x[j] = bf2f(v.u[j]);
        s += x[j];
        ss += x[j] * x[j];
    }
    #pragma unroll
    for (int o = 32; o > 0; o >>= 1) {
        s  += __shfl_xor(s, o, 64);
        ss += __shfl_xor(ss, o, 64);
    }
    float mean = s * (1.f / 512.f);
    float var  = ss * (1.f / 512.f) - mean * mean;
    float inv  = rsqrtf(var + 1e-5f);
    float4 g0 = *(const float4*)&g[lane * 8];
    float4 g1 = *(const float4*)&g[lane * 8 + 4];
    float4 b0 = *(const float4*)&be[lane * 8];
    float4 b1 = *(const float4*)&be[lane * 8 + 4];
    float gg[8] = {g0.x, g0.y, g0.z, g0.w, g1.x, g1.y, g1.z, g1.w};
    float bb[8] = {b0.x, b0.y, b0.z, b0.w, b1.x, b1.y, b1.z, b1.w};
    #pragma unroll
    for (int j = 0; j < 8; j++) {
        float y = (x[j] - mean) * inv * gg[j] + bb[j];
        v.u[j] = f2bf(0.5f * y * (1.f + erff(y * 0.70710678f)));
    }
    *(ushort8*)ip = v.u;
}

// ---------------------------------------------------------------------------
// cat[row][0:256] = desc (f32 pair) as bf16.
// ---------------------------------------------------------------------------
__global__ __launch_bounds__(256) void copy_to_cat(
    const float* __restrict__ s0, const float* __restrict__ s1,
    unsigned short* __restrict__ cat)
{
    int i = blockIdx.x * 256 + threadIdx.x;
    int row = i >> 6, c4 = (i & 63) * 4;
    const float* s = (row < NTOK) ? s0 : s1;
    float4 a = *(const float4*)&s[(size_t)(row & 8191) * 256 + c4];
    ushort4 p = { f2bf(a.x), f2bf(a.y), f2bf(a.z), f2bf(a.w) };
    *(ushort4*)&cat[(size_t)row * 512 + c4] = p;
}

// ---------------------------------------------------------------------------
extern "C" void kernel_launch(void* const* d_in, const int* in_sizes, int n_in,
                              void* d_out, int out_size, void* d_ws, size_t ws_size,
                              hipStream_t stream)
{
    const float* desc0 = (const float*)d_in[0];
    const float* desc1 = (const float*)d_in[1];
    const float* enc0  = (const float*)d_in[2];
    const float* enc1  = (const float*)d_in[3];
    const float* Wqkv  = (const float*)d_in[4];  const float* bqkv  = (const float*)d_in[5];
    const float* Wo_s  = (const float*)d_in[6];  const float* bo_s  = (const float*)d_in[7];
    const float* W1_s  = (const float*)d_in[8];  const float* b1_s  = (const float*)d_in[9];
    const float* g_s   = (const float*)d_in[10]; const float* be_s  = (const float*)d_in[11];
    const float* W2_s  = (const float*)d_in[12]; const float* b2_s  = (const float*)d_in[13];
    const float* Wqk_c = (const float*)d_in[14]; const float* bqk_c = (const float*)d_in[15];
    const float* Wv_c  = (const float*)d_in[16]; const float* bv_c  = (const float*)d_in[17];
    const float* Wo_c  = (const float*)d_in[18]; const float* bo_c  = (const float*)d_in[19];
    const float* W1_c  = (const float*)d_in[20]; const float* b1_c  = (const float*)d_in[21];
    const float* g_c   = (const float*)d_in[22]; const float* be_c  = (const float*)d_in[23];
    const float* W2_c  = (const float*)d_in[24]; const float* b2_c  = (const float*)d_in[25];

    char* ws = (char*)d_ws;
    unsigned short* wt  = (unsigned short*)ws;
    unsigned short* qb  = (unsigned short*)(ws + 2490368);
    unsigned short* kb  = (unsigned short*)(ws + 10878976);
    unsigned short* vb  = (unsigned short*)(ws + 27656192);         // V^T [32][64][2048]
    unsigned short* cat = (unsigned short*)(ws + 36044800);         // bf16 [16384][512]
    unsigned short* hb  = (unsigned short*)(ws + 52822016);         // bf16 [16384][512]
    unsigned short* dbf = (unsigned short*)(ws + 86376448);         // bf16 [16384][256]

    // composite-weight regions (shorts offsets into wt)
    unsigned short* t_qkv  = wt;                 // [768][256]
    float*          bias_s = (float*)(wt + 196608);   // 512 f32
    unsigned short* t_w1s  = wt + 262144;        // [512][512] composite
    unsigned short* t_w2s  = wt + 524288;        // [256][512]
    unsigned short* t_wqkc = wt + 655360;        // [512][256] (wqk rows + wv rows)
    float*          bias_c = (float*)(wt + 786432);   // 512 f32
    unsigned short* t_w1c  = wt + 851968;        // [512][512] composite
    unsigned short* t_w2c  = wt + 1114112;       // [256][512]

    float* outF = (float*)d_out;   // [16384][256]

    dim3 blk(256);

    // ---- prep: transpose/convert + weight-space Wo fusion ----
    WTab tab;
    tab.w[0] = Wqkv;  tab.o[0] = t_qkv;          tab.K[0] = 256; tab.N[0] = 768; tab.st[0] = 256;
    tab.w[1] = W1_s;  tab.o[1] = t_w1s;          tab.K[1] = 256; tab.N[1] = 512; tab.st[1] = 512;
    tab.w[2] = W2_s;  tab.o[2] = t_w2s;          tab.K[2] = 512; tab.N[2] = 256; tab.st[2] = 512;
    tab.w[3] = Wqk_c; tab.o[3] = t_wqkc;         tab.K[3] = 256; tab.N[3] = 256; tab.st[3] = 256;
    tab.w[4] = Wv_c;  tab.o[4] = t_wqkc + 65536; tab.K[4] = 256; tab.N[4] = 256; tab.st[4] = 256;
    tab.w[5] = W1_c;  tab.o[5] = t_w1c;          tab.K[5] = 256; tab.N[5] = 512; tab.st[5] = 512;
    tab.w[6] = W2_c;  tab.o[6] = t_w2c;          tab.K[6] = 512; tab.N[6] = 256; tab.st[6] = 512;
    int acc_t = 0;
    for (int s = 0; s < 7; s++) {
        tab.t0[s] = acc_t;
        acc_t += (tab.K[s] / 32) * (tab.N[s] / 32);
    }
    tab.t0[7] = acc_t;
    hipLaunchKernelGGL(wtrans, dim3(acc_t), blk, 0, stream, tab);
    hipLaunchKernelGGL(wfuse, dim3(128), blk, 0, stream,
                       Wo_s, W1_s, t_w1s, Wo_c, W1_c, t_w1c);
    hipLaunchKernelGGL(bfuse, dim3(1024), blk, 0, stream,
                       bo_s, W1_s, b1_s, bias_s, bo_c, W1_c, b1_c, bias_c);

    auto gemm = [&](const unsigned short* A, int lda, const unsigned short* Wtp,
                    int K, const float* bias, const float* bias2, int Nc, int mode,
                    float* oF, unsigned short* oh0, unsigned short* oh1,
                    unsigned short* oh2, int ldc, const float* r0, const float* r1) {
        dim3 g(Nc / 128, NTOK2 / 64);
        hipLaunchKernelGGL(gemm_mfma, g, blk, 0, stream,
                           A, lda, Wtp, K, bias, bias2, mode,
                           oF, oh0, oh1, oh2, ldc, r0, r1);
    };

    const float QS = 0.125f * 1.44269504088896f;

    // ---- self block (both streams batched) ----
    hipLaunchKernelGGL(copy_to_cat, dim3(4096), blk, 0, stream, desc0, desc1, cat);
    gemm(cat, 512, t_qkv, 256, bqkv, nullptr, 768, 3,
         nullptr, qb, kb, vb, 0, nullptr, nullptr);
    hipLaunchKernelGGL(rope_k, dim3(16384), blk, 0, stream, qb, kb, enc0, enc1);
    hipLaunchKernelGGL(flash_attn, dim3(NN / 64, 32), blk, 0, stream,
                       qb, kb, vb, cat + 256, 512, 0, QS);
    gemm(cat, 512, t_w1s, 512, bias_s, nullptr, 512, 1,
         nullptr, hb, nullptr, nullptr, 512, nullptr, nullptr);
    hipLaunchKernelGGL(ln_gelu, dim3(NTOK2 / 4), blk, 0, stream, hb, g_s, be_s);
    gemm(hb, 512, t_w2s, 512, b2_s, nullptr, 256, 4,
         outF, dbf, cat, nullptr, 256, desc0, desc1);

    // ---- cross block ----
    gemm(dbf, 256, t_wqkc, 256, bqk_c, bv_c, 512, 2,
         nullptr, qb, vb, nullptr, 0, nullptr, nullptr);
    hipLaunchKernelGGL(flash_attn, dim3(NN / 64, 32), blk, 0, stream,
                       qb, qb, vb, cat + 256, 512, 16, QS);
    gemm(cat, 512, t_w1c, 512, bias_c, nullptr, 512, 1,
         nullptr, hb, nullptr, nullptr, 512, nullptr, nullptr);
    hipLaunchKernelGGL(ln_gelu, dim3(NTOK2 / 4), blk, 0, stream, hb, g_c, be_c);
    gemm(hb, 512, t_w2c, 512, b2_c, nullptr, 256, 4,
         outF, nullptr, nullptr, nullptr, 256, outF, outF + (size_t)NTOK * 256);
}

// Round 13
// 458.803 us; speedup vs baseline: 1.2605x; 1.2605x over previous
//
#include <hip/hip_runtime.h>
#include <math.h>

#define BB 4
#define HH 4
#define NN 2048
#define DD 256
#define HDIM 64
#define NTOK 8192
#define NTOK2 16384

typedef __attribute__((ext_vector_type(8))) __bf16 bf16x8;
typedef __attribute__((ext_vector_type(8))) unsigned short ushort8;
typedef __attribute__((ext_vector_type(4))) float floatx4;
typedef __attribute__((ext_vector_type(4))) short short4v;

union U8 { ushort8 u; bf16x8 b; };
union U4 { unsigned int u[2]; unsigned long long l; short4v s; };

// v_mfma_f32_16x16x16_bf16 (K=16): A/B = 4 bf16 (short4), C/D = 4 f32.
#define MFMA16(a, b, c) __builtin_amdgcn_mfma_f32_16x16x16bf16_1k(a, b, c, 0, 0, 0)

__device__ __forceinline__ unsigned short f2bf(float x) {
    unsigned int u = __float_as_uint(x);
    u += 0x7FFF + ((u >> 16) & 1);
    return (unsigned short)(u >> 16);
}
__device__ __forceinline__ float bf2f(unsigned short u) {
    return __uint_as_float(((unsigned int)u) << 16);
}
// hardware packed f32->bf16 convert (RNE): lo16 = a, hi16 = b, one VALU op
__device__ __forceinline__ unsigned int cvtpk(float a, float b) {
    unsigned int r;
    asm("v_cvt_pk_bf16_f32 %0, %1, %2" : "=v"(r) : "v"(a), "v"(b));
    return r;
}
__device__ __forceinline__ floatx4 fmax4(floatx4 a, floatx4 b) {
    floatx4 r;
    r[0] = fmaxf(a[0], b[0]); r[1] = fmaxf(a[1], b[1]);
    r[2] = fmaxf(a[2], b[2]); r[3] = fmaxf(a[3], b[3]);
    return r;
}

// ---------------------------------------------------------------------------
// Weight transpose+convert: W[K][N] f32 -> Wt[N][st] bf16 (st = output row
// stride in k; lets W1 top-halves land in 512-stride composite buffers).
// ---------------------------------------------------------------------------
struct WTab {
    const float* w[7];
    unsigned short* o[7];
    int K[7];
    int N[7];
    int st[7];
    int t0[8];
};

__global__ __launch_bounds__(256) void wtrans(WTab tab)
{
    __shared__ float lds[32][33];
    const int t = threadIdx.x;
    int bid = blockIdx.x;
    int s = 0;
    while (bid >= tab.t0[s + 1]) s++;
    const int ti = bid - tab.t0[s];
    const int K = tab.K[s], N = tab.N[s], st = tab.st[s];
    const int tx = ti % (N / 32), ty = ti / (N / 32);
    const int k0 = ty * 32, n0 = tx * 32;
    const float* W = tab.w[s];
    unsigned short* Wt = tab.o[s];

    {
        int r = t >> 3, c = (t & 7) * 4;
        float4 a = *(const float4*)&W[(size_t)(k0 + r) * N + n0 + c];
        lds[r][c] = a.x; lds[r][c+1] = a.y; lds[r][c+2] = a.z; lds[r][c+3] = a.w;
    }
    __syncthreads();
    {
        int n = t >> 3, kq = (t & 7) * 4;
        ushort4 p;
        p.x = f2bf(lds[kq+0][n]); p.y = f2bf(lds[kq+1][n]);
        p.z = f2bf(lds[kq+2][n]); p.w = f2bf(lds[kq+3][n]);
        *(ushort4*)&Wt[(size_t)(n0 + n) * st + k0 + kq] = p;
    }
}

// ---------------------------------------------------------------------------
// Weight fusion: Weff_bot[i][n] = sum_j Wo[i][j] * W1[256+j][n], written
// transposed-bf16 into out[n][256+i] (512-stride).  grid 128: seg = bid>>6.
// ---------------------------------------------------------------------------
__global__ __launch_bounds__(256) void wfuse(
    const float* __restrict__ Wo_s, const float* __restrict__ W1_s,
    unsigned short* __restrict__ o_s,
    const float* __restrict__ Wo_c, const float* __restrict__ W1_c,
    unsigned short* __restrict__ o_c)
{
    __shared__ float wo[32][33];
    __shared__ float w1[32][68];
    const int t = threadIdx.x;
    const int bid = blockIdx.x;
    const int seg = bid >> 6, ti_ = bid & 63;
    const int i0 = (ti_ >> 3) * 32, n0 = (ti_ & 7) * 64;
    const float* Wo  = seg ? Wo_c : Wo_s;
    const float* W1b = (seg ? W1_c : W1_s) + 256 * 512;
    unsigned short* out = seg ? o_c : o_s;
    const int ti = t >> 3, tn = t & 7;

    float acc[8] = {};
    for (int jc = 0; jc < 256; jc += 32) {
        {
            int r = t >> 3, c = (t & 7) * 4;
            *(float4*)&wo[r][c] = *(const float4*)&Wo[(size_t)(i0 + r) * 256 + jc + c];
            int c8 = (t & 7) * 8;
            *(float4*)&w1[r][c8]     = *(const float4*)&W1b[(size_t)(jc + r) * 512 + n0 + c8];
            *(float4*)&w1[r][c8 + 4] = *(const float4*)&W1b[(size_t)(jc + r) * 512 + n0 + c8 + 4];
        }
        __syncthreads();
        #pragma unroll
        for (int j = 0; j < 32; j++) {
            float a = wo[ti][j];
            #pragma unroll
            for (int e = 0; e < 8; e++) acc[e] += a * w1[j][tn * 8 + e];
        }
        __syncthreads();
    }
    #pragma unroll
    for (int e = 0; e < 8; e++)
        out[(size_t)(n0 + tn * 8 + e) * 512 + 256 + i0 + ti] = f2bf(acc[e]);
}

// ---------------------------------------------------------------------------
// Bias fusion: beff[n] = b1[n] + sum_j bo[j] * W1[256+j][n].
// grid 1024 (seg*512 + n); block reduces the 256-term dot product.
// ---------------------------------------------------------------------------
__global__ __launch_bounds__(256) void bfuse(
    const float* bo_s, const float* W1_s, const float* b1_s, float* bs,
    const float* bo_c, const float* W1_c, const float* b1_c, float* bc)
{
    __shared__ float r[4];
    const int bid = blockIdx.x;
    const int seg = bid >> 9, n = bid & 511;
    const float* bo  = seg ? bo_c : bo_s;
    const float* W1b = (seg ? W1_c : W1_s) + 256 * 512;
    const float* b1  = seg ? b1_c : b1_s;
    float* out       = seg ? bc : bs;
    const int j = threadIdx.x;
    float a = bo[j] * W1b[(size_t)j * 512 + n];
    #pragma unroll
    for (int o = 32; o > 0; o >>= 1) a += __shfl_xor(a, o, 64);
    if ((j & 63) == 0) r[j >> 6] = a;
    __syncthreads();
    if (j == 0) out[n] = b1[n] + r[0] + r[1] + r[2] + r[3];
}

// ---------------------------------------------------------------------------
// bf16 MFMA GEMM, 64x128 tile, register-staged, BK=64 (half the K-steps of
// the BK=32 variant -> half the barrier crossings and exposed-latency
// windows).  LDS rows padded to 72 shorts; 2-barrier loop order identical
// to the measured-best R5 structure.  MEASURED OPTIMUM of all structures
// tried: global_load_lds (R2/R4), BM=128 (R6), dbuf 1-barrier (R7),
// RoPE-fused epilogue (R9), zero-LDS direct-from-L2 (R12) all regressed.
// modes: 1 bf16 row-major | 2 bf16 dual scatter (col<256 -> rows [bh][n][d],
//        col>=256 -> V^T [bh][d][n]) | 3 qkv scatter (V transposed) |
//        4 f32 = acc+bias+R (+ bf16 copies to outH0 [.,256] / outH1 [.,512])
// ---------------------------------------------------------------------------
__global__ __launch_bounds__(256) void gemm_mfma(
    const unsigned short* __restrict__ A, int lda,
    const unsigned short* __restrict__ Wt, int K,
    const float* __restrict__ bias, const float* __restrict__ bias2, int mode,
    float* outF, unsigned short* outH0, unsigned short* outH1,
    unsigned short* outH2,
    int ldc, const float* R0, const float* R1)
{
    __shared__ __align__(16) unsigned short As[64 * 72];
    __shared__ __align__(16) unsigned short Bs[128 * 72];
    const int t = threadIdx.x;
    const int w = t >> 6, lane = t & 63, quad = lane >> 4, l15 = lane & 15;
    const int m0 = blockIdx.y * 64, n0 = blockIdx.x * 128;
    const int wn = w * 32;
    // A: 64 rows x 64 K = 8KB; thread t covers row t>>2, 32B at (t&3)*16
    const int sar = t >> 2, sac = (t & 3) * 16;
    // B: 128 rows x 64 K = 16KB; thread t covers row t>>1, 64B at (t&1)*32
    const int sbr = t >> 1, sbc = (t & 1) * 32;

    const unsigned short* Ap = A  + (size_t)(m0 + sar) * lda + sac;
    const unsigned short* Bp = Wt + (size_t)(n0 + sbr) * K   + sbc;

    ushort8 pa0 = *(const ushort8*)(Ap);
    ushort8 pa1 = *(const ushort8*)(Ap + 8);
    ushort8 pb0 = *(const ushort8*)(Bp);
    ushort8 pb1 = *(const ushort8*)(Bp + 8);
    ushort8 pb2 = *(const ushort8*)(Bp + 16);
    ushort8 pb3 = *(const ushort8*)(Bp + 24);

    floatx4 acc[4][2];
    #pragma unroll
    for (int i = 0; i < 4; i++)
        #pragma unroll
        for (int j = 0; j < 2; j++) acc[i][j] = (floatx4){0.f, 0.f, 0.f, 0.f};

    const int nk = K >> 6;
    for (int kk = 0; kk < nk; kk++) {
        *(ushort8*)&As[sar * 72 + sac]      = pa0;
        *(ushort8*)&As[sar * 72 + sac + 8]  = pa1;
        *(ushort8*)&Bs[sbr * 72 + sbc]      = pb0;
        *(ushort8*)&Bs[sbr * 72 + sbc + 8]  = pb1;
        *(ushort8*)&Bs[sbr * 72 + sbc + 16] = pb2;
        *(ushort8*)&Bs[sbr * 72 + sbc + 24] = pb3;
        __syncthreads();
        if (kk + 1 < nk) {
            int ko = (kk + 1) * 64;
            pa0 = *(const ushort8*)(Ap + ko);
            pa1 = *(const ushort8*)(Ap + ko + 8);
            pb0 = *(const ushort8*)(Bp + ko);
            pb1 = *(const ushort8*)(Bp + ko + 8);
            pb2 = *(const ushort8*)(Bp + ko + 16);
            pb3 = *(const ushort8*)(Bp + ko + 24);
        }
        #pragma unroll
        for (int kh = 0; kh < 2; kh++) {
            U8 af[4], bf[2];
            #pragma unroll
            for (int i = 0; i < 4; i++)
                af[i].u = *(const ushort8*)&As[(i * 16 + l15) * 72 + kh * 32 + quad * 8];
            #pragma unroll
            for (int j = 0; j < 2; j++)
                bf[j].u = *(const ushort8*)&Bs[(wn + j * 16 + l15) * 72 + kh * 32 + quad * 8];
            #pragma unroll
            for (int i = 0; i < 4; i++)
                #pragma unroll
                for (int j = 0; j < 2; j++)
                    acc[i][j] = __builtin_amdgcn_mfma_f32_16x16x32_bf16(af[i].b, bf[j].b, acc[i][j], 0, 0, 0);
        }
        __syncthreads();
    }

    #pragma unroll
    for (int i = 0; i < 4; i++) {
        #pragma unroll
        for (int j = 0; j < 2; j++) {
            int col = n0 + wn + j * 16 + l15;
            float bv = (mode == 2 && col >= 256) ? bias2[col & 255] : bias[col];
            #pragma unroll
            for (int r = 0; r < 4; r++) {
                int grow = m0 + i * 16 + quad * 4 + r;
                float v = acc[i][j][r] + bv;
                if (mode == 1) {
                    outH0[(size_t)grow * ldc + col] = f2bf(v);
                } else if (mode == 2) {
                    int cc = col & 255;
                    int h = cc >> 6, d = cc & 63;
                    int ds = grow >> 13, b = (grow >> 11) & 3, n = grow & 2047;
                    int bh = ds * 16 + b * 4 + h;
                    if (col < 256)
                        outH0[((size_t)bh * NN + n) * HDIM + d] = f2bf(v);
                    else  // V^T layout [bh][hd][n]
                        outH1[((size_t)bh * HDIM + d) * NN + n] = f2bf(v);
                } else if (mode == 3) {
                    int sel = col % 3, cc = col / 3;
                    int h = cc >> 6, d = cc & 63;
                    int ds = grow >> 13, b = (grow >> 11) & 3, n = grow & 2047;
                    int bh = ds * 16 + b * 4 + h;
                    if (sel == 0)
                        outH0[((size_t)bh * NN + n) * HDIM + d] = f2bf(v);
                    else if (sel == 1)
                        outH1[((size_t)bh * NN + n) * HDIM + d] = f2bf(v);
                    else  // V^T layout [bh][hd][n]
                        outH2[((size_t)bh * HDIM + d) * NN + n] = f2bf(v);
                } else {
                    const float* R = (grow < NTOK) ? R0 : R1;
                    float vv = v + R[(size_t)(grow & 8191) * 256 + col];
                    outF[(size_t)grow * 256 + col] = vv;
                    if (outH0) outH0[(size_t)grow * 256 + col] = f2bf(vv);
                    if (outH1) outH1[(size_t)grow * 512 + col] = f2bf(vv);
                }
            }
        }
    }
}

// ---------------------------------------------------------------------------
// RoPE in place on qb and kb (bf16 [32][2048][64]); enc0/enc1 f32 [2,B,1,N,HD].
// ---------------------------------------------------------------------------
__global__ __launch_bounds__(256) void rope_k(unsigned short* __restrict__ qb,
                                              unsigned short* __restrict__ kb,
                                              const float* __restrict__ enc0,
                                              const float* __restrict__ enc1)
{
    int i = blockIdx.x * 256 + threadIdx.x;     // 2^22 pair slots
    int dp = (i & 31) * 2;
    int n  = (i >> 5) & (NN - 1);
    int h  = (i >> 16) & 3;
    int b  = (i >> 18) & 3;
    int ds = (i >> 20) & 1;
    int bf = (i >> 21) & 1;
    unsigned short* tq = (bf ? kb : qb) +
        (((size_t)(ds * 16 + b * 4 + h)) * NN + n) * HDIM + dp;
    const float* e0 = (ds ? enc1 : enc0) + ((size_t)b * NN + n) * HDIM + dp;
    const float* e1 = e0 + (size_t)BB * NN * HDIM;
    float x0 = bf2f(tq[0]), x1 = bf2f(tq[1]);
    float y0 = x0 * e0[0] - x1 * e1[0];
    float y1 = x1 * e0[1] + x0 * e1[1];
    tq[0] = f2bf(y0); tq[1] = f2bf(y1);
}

// ---------------------------------------------------------------------------
// MFMA bf16 flash attention, S^T formulation.  Q,K row-major [32][2048][64];
// V PRE-TRANSPOSED [32][64][2048].  QBLK=64: each of 4 waves owns 16 q-rows
// (single MFMA group) -> grid 1024 blocks = 4 blocks/CU.  KVBLK=64 double-
// buffered LDS, single __syncthreads per step.  Per-lane online softmax with
// defer-max rescale skip (THR=8, exp2 domain), v_cvt_pk_bf16_f32 packing,
// cross-quad l-reduction deferred to the epilogue.  ISSUE-SATURATED at this
// point (VALU 70% + MFMA 24%): flash's floor for this algorithm.
// KV head = bh ^ kvx.  qscale incl log2e.
// ---------------------------------------------------------------------------
__global__ __launch_bounds__(256) void flash_attn(
    const unsigned short* __restrict__ Q, const unsigned short* __restrict__ K,
    const unsigned short* __restrict__ V, unsigned short* __restrict__ O,
    int ldo, int kvx, float qscale)
{
    __shared__ __align__(16) unsigned short Ks[2][64 * 72];    // [key][hd]
    __shared__ __align__(16) unsigned short Vt[2][64 * 72];    // [hd][key]

    const int t    = threadIdx.x;
    const int w    = t >> 6;
    const int lane = t & 63;
    const int quad = lane >> 4;
    const int l15  = lane & 15;
    const int bh   = blockIdx.y;
    const int kbh  = bh ^ kvx;
    const int q0   = blockIdx.x * 64;

    const unsigned short* Qb  = Q + (size_t)bh  * NN * HDIM;
    const unsigned short* Kb  = K + (size_t)kbh * NN * HDIM;
    const unsigned short* VTb = V + (size_t)kbh * NN * HDIM;   // [hd][n]

    const int srf = t >> 3, scf = (t & 7) * 8;

    // Q fragments: lane l15 = q-row, k(hd) = quad*8+j  (B-operand of K·Q^T)
    bf16x8 qf0, qf1;
    {
        const int qrow = q0 + w * 16 + l15;
        U8 r0, r1, x0, x1;
        r0.u = *(const ushort8*)&Qb[(size_t)qrow * HDIM + quad * 8];
        r1.u = *(const ushort8*)&Qb[(size_t)qrow * HDIM + 32 + quad * 8];
        #pragma unroll
        for (int j = 0; j < 8; j++) {
            x0.u[j] = f2bf(bf2f(r0.u[j]) * qscale);
            x1.u[j] = f2bf(bf2f(r1.u[j]) * qscale);
        }
        qf0 = x0.b; qf1 = x1.b;
    }

    floatx4 o[4];   // O^T accumulator: col = q = l15, row(hd) = c*16+quad*4+r
    #pragma unroll
    for (int c = 0; c < 4; c++) o[c] = (floatx4){0.f, 0.f, 0.f, 0.f};
    float m = -1e30f, l = 0.f;   // l is a per-lane PARTIAL (this quad's keys)

    // tile 0: load + stage into buffer 0
    ushort8 ka0 = *(const ushort8*)&Kb[(size_t)srf * HDIM + scf];
    ushort8 ka1 = *(const ushort8*)&Kb[(size_t)(srf + 32) * HDIM + scf];
    ushort8 va0 = *(const ushort8*)&VTb[(size_t)srf * NN + scf];
    ushort8 va1 = *(const ushort8*)&VTb[(size_t)(srf + 32) * NN + scf];
    *(ushort8*)&Ks[0][srf * 72 + scf]        = ka0;
    *(ushort8*)&Ks[0][(srf + 32) * 72 + scf] = ka1;
    *(ushort8*)&Vt[0][srf * 72 + scf]        = va0;
    *(ushort8*)&Vt[0][(srf + 32) * 72 + scf] = va1;
    __syncthreads();

    int cur = 0;
    for (int j0 = 0; j0 < NN; j0 += 64, cur ^= 1) {
        const int more = (j0 + 64 < NN);
        if (more) {
            const int jn = j0 + 64;
            ka0 = *(const ushort8*)&Kb[(size_t)(jn + srf) * HDIM + scf];
            ka1 = *(const ushort8*)&Kb[(size_t)(jn + srf + 32) * HDIM + scf];
            va0 = *(const ushort8*)&VTb[(size_t)srf * NN + jn + scf];
            va1 = *(const ushort8*)&VTb[(size_t)(srf + 32) * NN + jn + scf];
        }

        // S^T = K (qscale*Q)^T : s[t4]: col = q = l15, row(key) = quad*4 + r
        floatx4 s[4];
        __builtin_amdgcn_s_setprio(1);
        #pragma unroll
        for (int t4 = 0; t4 < 4; t4++) {
            U8 k0, k1;
            k0.u = *(const ushort8*)&Ks[cur][(t4 * 16 + l15) * 72 + quad * 8];
            k1.u = *(const ushort8*)&Ks[cur][(t4 * 16 + l15) * 72 + 32 + quad * 8];
            floatx4 z = (floatx4){0.f, 0.f, 0.f, 0.f};
            z = __builtin_amdgcn_mfma_f32_16x16x32_bf16(k0.b, qf0, z, 0, 0, 0);
            z = __builtin_amdgcn_mfma_f32_16x16x32_bf16(k1.b, qf1, z, 0, 0, 0);
            s[t4] = z;
        }
        __builtin_amdgcn_s_setprio(0);

        // per-lane online softmax (one q-row per lane; keys split across quads)
        floatx4 a = fmax4(fmax4(s[0], s[1]), fmax4(s[2], s[3]));
        float mx = fmaxf(fmaxf(a[0], a[1]), fmaxf(a[2], a[3]));
        mx = fmaxf(mx, __shfl_xor(mx, 16, 64));
        mx = fmaxf(mx, __shfl_xor(mx, 32, 64));
        // defer-max: skip the O/l rescale while max growth stays < 8
        // (exp2 domain -> P bounded by 256; harmless in f32 accum)
        if (!__all(mx <= m + 8.f)) {
            float mn = fmaxf(m, mx);
            float al = exp2f(m - mn);
            m = mn;
            l *= al;
            #pragma unroll
            for (int c = 0; c < 4; c++)
                #pragma unroll
                for (int r = 0; r < 4; r++) o[c][r] *= al;
        }
        float rs = 0.f;
        #pragma unroll
        for (int t4 = 0; t4 < 4; t4++)
            #pragma unroll
            for (int r = 0; r < 4; r++) {
                float p = exp2f(s[t4][r] - m);
                s[t4][r] = p;
                rs += p;
            }
        l += rs;   // per-lane partial; cross-quad reduce deferred to epilogue

        // pack P^T fragments: C/D layout of S^T == B-operand of 16x16x16
        short4v pf[4];
        #pragma unroll
        for (int t4 = 0; t4 < 4; t4++) {
            U4 pk;
            pk.u[0] = cvtpk(s[t4][0], s[t4][1]);
            pk.u[1] = cvtpk(s[t4][2], s[t4][3]);
            pf[t4] = pk.s;
        }

        // O^T += V^T P^T : A = V^T chunk [hd=c*16+l15][key=t4*16+quad*4+j]
        __builtin_amdgcn_s_setprio(1);
        #pragma unroll
        for (int c = 0; c < 4; c++) {
            U4 vf[4];
            #pragma unroll
            for (int t4 = 0; t4 < 4; t4++)
                vf[t4].l = *(const unsigned long long*)
                    &Vt[cur][(c * 16 + l15) * 72 + t4 * 16 + quad * 4];
            #pragma unroll
            for (int t4 = 0; t4 < 4; t4++)
                o[c] = MFMA16(vf[t4].s, pf[t4], o[c]);
        }
        __builtin_amdgcn_s_setprio(0);

        // stage next tile into the other buffer; single barrier per step
        // (safe: buf cur^1 was last read before the PREVIOUS barrier)
        if (more) {
            *(ushort8*)&Ks[cur ^ 1][srf * 72 + scf]        = ka0;
            *(ushort8*)&Ks[cur ^ 1][(srf + 32) * 72 + scf] = ka1;
            *(ushort8*)&Vt[cur ^ 1][srf * 72 + scf]        = va0;
            *(ushort8*)&Vt[cur ^ 1][(srf + 32) * 72 + scf] = va1;
            __syncthreads();
        }
    }

    // epilogue: cross-quad l reduce, normalize, write bf16 at stride ldo
    l += __shfl_xor(l, 16, 64);
    l += __shfl_xor(l, 32, 64);
    const int ds = bh >> 4, b = (bh >> 2) & 3, h = bh & 3;
    const int q = q0 + w * 16 + l15;
    const size_t row = (size_t)ds * NTOK + b * NN + q;
    float inv = 1.f / l;
    #pragma unroll
    for (int c = 0; c < 4; c++) {
        U4 pk;
        pk.u[0] = cvtpk(o[c][0] * inv, o[c][1] * inv);
        pk.u[1] = cvtpk(o[c][2] * inv, o[c][3] * inv);
        *(unsigned long long*)&O[row * ldo + h * HDIM + c * 16 + quad * 4] = pk.l;
    }
}

// ---------------------------------------------------------------------------
// LayerNorm + exact GELU, bf16 in-place, row width 512.
// One WAVE per row (64 lanes x 8 elems, ushort8 vector loads), pure-shuffle
// reduction, no LDS, no barrier.  Block = 4 waves = 4 rows.
// ---------------------------------------------------------------------------
__global__ __launch_bounds__(256) void ln_gelu(
    unsigned short* __restrict__ hb, const float* __restrict__ g,
    const float* __restrict__ be)
{
    const int lane = threadIdx.x & 63;
    const int wv   = threadIdx.x >> 6;
    const size_t row = (size_t)blockIdx.x * 4 + wv;
    unsigned short* ip = hb + row * 512 + lane * 8;
    U8 v; v.u = *(const ushort8*)ip;
    float x[8];
    float s = 0.f, ss = 0.f;
    #pragma unroll
    for (int j = 0; j < 8; j++) {
        x[j] = bf2f(v.u[j]);
        s += x[j];
        ss += x[j] * x[j];
    }
    #pragma unroll
    for (int o = 32; o > 0; o >>= 1) {
        s  += __shfl_xor(s, o, 64);
        ss += __shfl_xor(ss, o, 64);
    }
    float mean = s * (1.f / 512.f);
    float var  = ss * (1.f / 512.f) - mean * mean;
    float inv  = rsqrtf(var + 1e-5f);
    float4 g0 = *(const float4*)&g[lane * 8];
    float4 g1 = *(const float4*)&g[lane * 8 + 4];
    float4 b0 = *(const float4*)&be[lane * 8];
    float4 b1 = *(const float4*)&be[lane * 8 + 4];
    float gg[8] = {g0.x, g0.y, g0.z, g0.w, g1.x, g1.y, g1.z, g1.w};
    float bb[8] = {b0.x, b0.y, b0.z, b0.w, b1.x, b1.y, b1.z, b1.w};
    #pragma unroll
    for (int j = 0; j < 8; j++) {
        float y = (x[j] - mean) * inv * gg[j] + bb[j];
        v.u[j] = f2bf(0.5f * y * (1.f + erff(y * 0.70710678f)));
    }
    *(ushort8*)ip = v.u;
}

// ---------------------------------------------------------------------------
// cat[row][0:256] = desc (f32 pair) as bf16.
// ---------------------------------------------------------------------------
__global__ __launch_bounds__(256) void copy_to_cat(
    const float* __restrict__ s0, const float* __restrict__ s1,
    unsigned short* __restrict__ cat)
{
    int i = blockIdx.x * 256 + threadIdx.x;
    int row = i >> 6, c4 = (i & 63) * 4;
    const float* s = (row < NTOK) ? s0 : s1;
    float4 a = *(const float4*)&s[(size_t)(row & 8191) * 256 + c4];
    ushort4 p = { f2bf(a.x), f2bf(a.y), f2bf(a.z), f2bf(a.w) };
    *(ushort4*)&cat[(size_t)row * 512 + c4] = p;
}

// ---------------------------------------------------------------------------
extern "C" void kernel_launch(void* const* d_in, const int* in_sizes, int n_in,
                              void* d_out, int out_size, void* d_ws, size_t ws_size,
                              hipStream_t stream)
{
    const float* desc0 = (const float*)d_in[0];
    const float* desc1 = (const float*)d_in[1];
    const float* enc0  = (const float*)d_in[2];
    const float* enc1  = (const float*)d_in[3];
    const float* Wqkv  = (const float*)d_in[4];  const float* bqkv  = (const float*)d_in[5];
    const float* Wo_s  = (const float*)d_in[6];  const float* bo_s  = (const float*)d_in[7];
    const float* W1_s  = (const float*)d_in[8];  const float* b1_s  = (const float*)d_in[9];
    const float* g_s   = (const float*)d_in[10]; const float* be_s  = (const float*)d_in[11];
    const float* W2_s  = (const float*)d_in[12]; const float* b2_s  = (const float*)d_in[13];
    const float* Wqk_c = (const float*)d_in[14]; const float* bqk_c = (const float*)d_in[15];
    const float* Wv_c  = (const float*)d_in[16]; const float* bv_c  = (const float*)d_in[17];
    const float* Wo_c  = (const float*)d_in[18]; const float* bo_c  = (const float*)d_in[19];
    const float* W1_c  = (const float*)d_in[20]; const float* b1_c  = (const float*)d_in[21];
    const float* g_c   = (const float*)d_in[22]; const float* be_c  = (const float*)d_in[23];
    const float* W2_c  = (const float*)d_in[24]; const float* b2_c  = (const float*)d_in[25];

    char* ws = (char*)d_ws;
    unsigned short* wt  = (unsigned short*)ws;
    unsigned short* qb  = (unsigned short*)(ws + 2490368);
    unsigned short* kb  = (unsigned short*)(ws + 10878976);
    unsigned short* vb  = (unsigned short*)(ws + 27656192);         // V^T [32][64][2048]
    unsigned short* cat = (unsigned short*)(ws + 36044800);         // bf16 [16384][512]
    unsigned short* hb  = (unsigned short*)(ws + 52822016);         // bf16 [16384][512]
    unsigned short* dbf = (unsigned short*)(ws + 86376448);         // bf16 [16384][256]

    // composite-weight regions (shorts offsets into wt)
    unsigned short* t_qkv  = wt;                 // [768][256]
    float*          bias_s = (float*)(wt + 196608);   // 512 f32
    unsigned short* t_w1s  = wt + 262144;        // [512][512] composite
    unsigned short* t_w2s  = wt + 524288;        // [256][512]
    unsigned short* t_wqkc = wt + 655360;        // [512][256] (wqk rows + wv rows)
    float*          bias_c = (float*)(wt + 786432);   // 512 f32
    unsigned short* t_w1c  = wt + 851968;        // [512][512] composite
    unsigned short* t_w2c  = wt + 1114112;       // [256][512]

    float* outF = (float*)d_out;   // [16384][256]

    dim3 blk(256);

    // ---- prep: transpose/convert + weight-space Wo fusion ----
    WTab tab;
    tab.w[0] = Wqkv;  tab.o[0] = t_qkv;          tab.K[0] = 256; tab.N[0] = 768; tab.st[0] = 256;
    tab.w[1] = W1_s;  tab.o[1] = t_w1s;          tab.K[1] = 256; tab.N[1] = 512; tab.st[1] = 512;
    tab.w[2] = W2_s;  tab.o[2] = t_w2s;          tab.K[2] = 512; tab.N[2] = 256; tab.st[2] = 512;
    tab.w[3] = Wqk_c; tab.o[3] = t_wqkc;         tab.K[3] = 256; tab.N[3] = 256; tab.st[3] = 256;
    tab.w[4] = Wv_c;  tab.o[4] = t_wqkc + 65536; tab.K[4] = 256; tab.N[4] = 256; tab.st[4] = 256;
    tab.w[5] = W1_c;  tab.o[5] = t_w1c;          tab.K[5] = 256; tab.N[5] = 512; tab.st[5] = 512;
    tab.w[6] = W2_c;  tab.o[6] = t_w2c;          tab.K[6] = 512; tab.N[6] = 256; tab.st[6] = 512;
    int acc_t = 0;
    for (int s = 0; s < 7; s++) {
        tab.t0[s] = acc_t;
        acc_t += (tab.K[s] / 32) * (tab.N[s] / 32);
    }
    tab.t0[7] = acc_t;
    hipLaunchKernelGGL(wtrans, dim3(acc_t), blk, 0, stream, tab);
    hipLaunchKernelGGL(wfuse, dim3(128), blk, 0, stream,
                       Wo_s, W1_s, t_w1s, Wo_c, W1_c, t_w1c);
    hipLaunchKernelGGL(bfuse, dim3(1024), blk, 0, stream,
                       bo_s, W1_s, b1_s, bias_s, bo_c, W1_c, b1_c, bias_c);

    auto gemm = [&](const unsigned short* A, int lda, const unsigned short* Wtp,
                    int K, const float* bias, const float* bias2, int Nc, int mode,
                    float* oF, unsigned short* oh0, unsigned short* oh1,
                    unsigned short* oh2, int ldc, const float* r0, const float* r1) {
        dim3 g(Nc / 128, NTOK2 / 64);
        hipLaunchKernelGGL(gemm_mfma, g, blk, 0, stream,
                           A, lda, Wtp, K, bias, bias2, mode,
                           oF, oh0, oh1, oh2, ldc, r0, r1);
    };

    const float QS = 0.125f * 1.44269504088896f;

    // ---- self block (both streams batched) ----
    hipLaunchKernelGGL(copy_to_cat, dim3(4096), blk, 0, stream, desc0, desc1, cat);
    gemm(cat, 512, t_qkv, 256, bqkv, nullptr, 768, 3,
         nullptr, qb, kb, vb, 0, nullptr, nullptr);
    hipLaunchKernelGGL(rope_k, dim3(16384), blk, 0, stream, qb, kb, enc0, enc1);
    hipLaunchKernelGGL(flash_attn, dim3(NN / 64, 32), blk, 0, stream,
                       qb, kb, vb, cat + 256, 512, 0, QS);
    gemm(cat, 512, t_w1s, 512, bias_s, nullptr, 512, 1,
         nullptr, hb, nullptr, nullptr, 512, nullptr, nullptr);
    hipLaunchKernelGGL(ln_gelu, dim3(NTOK2 / 4), blk, 0, stream, hb, g_s, be_s);
    gemm(hb, 512, t_w2s, 512, b2_s, nullptr, 256, 4,
         outF, dbf, cat, nullptr, 256, desc0, desc1);

    // ---- cross block ----
    gemm(dbf, 256, t_wqkc, 256, bqk_c, bv_c, 512, 2,
         nullptr, qb, vb, nullptr, 0, nullptr, nullptr);
    hipLaunchKernelGGL(flash_attn, dim3(NN / 64, 32), blk, 0, stream,
                       qb, qb, vb, cat + 256, 512, 16, QS);
    gemm(cat, 512, t_w1c, 512, bias_c, nullptr, 512, 1,
         nullptr, hb, nullptr, nullptr, 512, nullptr, nullptr);
    hipLaunchKernelGGL(ln_gelu, dim3(NTOK2 / 4), blk, 0, stream, hb, g_c, be_c);
    gemm(hb, 512, t_w2c, 512, b2_c, nullptr, 256, 4,
         outF, nullptr, nullptr, nullptr, 256, outF, outF + (size_t)NTOK * 256);
}